// Round 8
// baseline (153.314 us; speedup 1.0000x reference)
//
#include <hip/hip_runtime.h>
#include <math.h>

// GlobalAttention, single-streaming-pass version (v8).
//   logits[b,h,n] = qW[h,:].LN(x[b,n,:])  (q folded through Wkv_k, LN folded via mu/rstd)
//   s[b,h,:]      = sum_n softmax(logits) * rstd_n * x[b,n,:]  (chunk partials, merged)
//   out           = cf + (Wkv_v @ (gamma*(S-UN)/E + beta)) @ proj_W.T + proj_b
// v8: NO LDS, NO sync barriers in the hot loop. Each wave (2 heads) streams all
// 64 rows global->reg (ping-pong 1 row deep); the 4 waves of a block read the
// same lines nearly simultaneously -> L1/L2 absorb the 4x amplification. Row
// stats computed redundantly per wave (cheaper than the barrier convoy they
// replace). Bare s_barrier every 4 rows ONLY to bound wave drift (keeps the
// block's read window L1/L2-resident); it drains nothing.

#define BB 16
#define NN 4096
#define CC 1024
#define HH 8
#define DD 128
#define CHUNKS 64   // chunks per batch
#define RPB 64      // rows per block

constexpr float EPS_ = 1e-5f;
constexpr float SCALE_ = 0.03125f; // 1024^-0.5

__device__ __forceinline__ float wsum(float v) {
#pragma unroll
  for (int o = 32; o; o >>= 1) v += __shfl_xor(v, o, 64);
  return v;
}

// DPP wave reduction: sum of all 64 lanes lands in lane 63 (VALU pipe, no LDS).
__device__ __forceinline__ float dpp_sum63(float v) {
  int t;
  t = __builtin_amdgcn_update_dpp(0, __float_as_int(v), 0x111, 0xf, 0xf, true);  v += __int_as_float(t);
  t = __builtin_amdgcn_update_dpp(0, __float_as_int(v), 0x112, 0xf, 0xf, true);  v += __int_as_float(t);
  t = __builtin_amdgcn_update_dpp(0, __float_as_int(v), 0x114, 0xf, 0xf, true);  v += __int_as_float(t);
  t = __builtin_amdgcn_update_dpp(0, __float_as_int(v), 0x118, 0xf, 0xf, true);  v += __int_as_float(t);
  t = __builtin_amdgcn_update_dpp(0, __float_as_int(v), 0x142, 0xa, 0xf, false); v += __int_as_float(t);
  t = __builtin_amdgcn_update_dpp(0, __float_as_int(v), 0x143, 0xc, 0xf, false); v += __int_as_float(t);
  return v;
}

// reduce + broadcast: total of 64 lanes as a wave-uniform value
__device__ __forceinline__ float rsum_u(float v) {
  return __int_as_float(__builtin_amdgcn_readlane(__float_as_int(dpp_sum63(v)), 63));
}

__device__ __forceinline__ float dot4(const float4& a, const float4& b) {
  return a.x * b.x + a.y * b.y + a.z * b.z + a.w * b.w;
}
__device__ __forceinline__ void fma4(float4& a, float s, const float4& v) {
  a.x += s * v.x; a.y += s * v.y; a.z += s * v.z; a.w += s * v.w;
}

// ---- k0b: LN(class_feature) in-block, then qvec[j] = ln_cf . Wq[j,:] ----
__global__ __launch_bounds__(256) void k0b(const float* __restrict__ cf,
                                           const float* __restrict__ g,
                                           const float* __restrict__ be,
                                           const float* __restrict__ Wq,
                                           float* __restrict__ qvec) {
  __shared__ __align__(16) float lnbuf[CC];
  __shared__ float red[8];
  int t = threadIdx.x, lane = t & 63, wid = t >> 6;
  float x[4];
  float s = 0.f, s2 = 0.f;
#pragma unroll
  for (int j = 0; j < 4; ++j) {
    x[j] = cf[t * 4 + j];
    s += x[j];
    s2 += x[j] * x[j];
  }
  s = wsum(s);
  s2 = wsum(s2);
  if (lane == 0) { red[wid] = s; red[4 + wid] = s2; }
  __syncthreads();
  float S = red[0] + red[1] + red[2] + red[3];
  float S2 = red[4] + red[5] + red[6] + red[7];
  float mu = S * (1.f / CC);
  float rstd = rsqrtf(S2 * (1.f / CC) - mu * mu + EPS_);
#pragma unroll
  for (int j = 0; j < 4; ++j)
    lnbuf[t * 4 + j] = (x[j] - mu) * rstd * g[t * 4 + j] + be[t * 4 + j];
  __syncthreads();
  int j = blockIdx.x * 4 + wid;
  const float4* wr = (const float4*)(Wq + (size_t)j * CC);
  const float4* l4 = (const float4*)lnbuf;
  float a = 0.f;
#pragma unroll
  for (int k = 0; k < 4; ++k) a += dot4(wr[lane + 64 * k], l4[lane + 64 * k]);
  a = wsum(a);
  if (lane == 0) qvec[j] = a;
}

// ---- k0c: qW[h,c] = scale*sum_d qvec[h*D+d]*Wkv[h*D+d,c]; qWg = qW*gamma ----
__global__ __launch_bounds__(256) void k0c(const float* __restrict__ qvec,
                                           const float* __restrict__ Wkv,
                                           const float* __restrict__ kvg,
                                           float* __restrict__ qW,
                                           float* __restrict__ qWg) {
  int h = blockIdx.x >> 4;
  int c0 = (blockIdx.x & 15) * 64;
  int t = threadIdx.x, cl = t & 63, g = t >> 6;
  float a = 0.f;
#pragma unroll 8
  for (int d = g * 32; d < g * 32 + 32; ++d)
    a += qvec[h * DD + d] * Wkv[((size_t)(h * DD + d)) * CC + c0 + cl];
  __shared__ float red[4][64];
  red[g][cl] = a;
  __syncthreads();
  if (t < 64) {
    float v = (red[0][t] + red[1][t] + red[2][t] + red[3][t]) * SCALE_;
    qW[h * CC + c0 + t] = v;
    qWg[h * CC + c0 + t] = v * kvg[c0 + t];
  }
}

// ---- fused single pass over x (v8: no LDS, no drain-barriers) ----
__global__ __launch_bounds__(256, 2) void kfused(
    const float* __restrict__ x, const float* __restrict__ qWg,
    const float* __restrict__ qW, const float* __restrict__ kvb,
    float* __restrict__ part_s, float* __restrict__ part_meu) {
  const int t = threadIdx.x, lane = t & 63, wid = t >> 6;
  const int chunk = blockIdx.x, b = blockIdx.y;
  const int bc = b * CHUNKS + chunk;
  const int h0 = wid * 2;

  const float4* gx = (const float4*)(x + ((size_t)b * NN + (size_t)chunk * RPB) * CC);

  // this wave's two heads' qWg fragments (live across the whole loop)
  float4 qw0[4], qw1[4];
  {
    const float4* a0 = (const float4*)(qWg + (size_t)h0 * CC);
    const float4* a1 = (const float4*)(qWg + (size_t)(h0 + 1) * CC);
#pragma unroll
    for (int k = 0; k < 4; ++k) {
      qw0[k] = a0[lane + 64 * k];
      qw1[k] = a1[lane + 64 * k];
    }
  }
  // qs = sum(qWg[h,:]); qb = qW[h,:].beta  (wave-uniform)
  float qs0, qs1, qb0, qb1;
  {
    float s0 = 0.f, s1 = 0.f, t0 = 0.f, t1 = 0.f;
    const float4* w0 = (const float4*)(qW + (size_t)h0 * CC);
    const float4* w1 = (const float4*)(qW + (size_t)(h0 + 1) * CC);
    const float4* b4 = (const float4*)kvb;
#pragma unroll
    for (int k = 0; k < 4; ++k) {
      s0 += qw0[k].x + qw0[k].y + qw0[k].z + qw0[k].w;
      s1 += qw1[k].x + qw1[k].y + qw1[k].z + qw1[k].w;
      float4 bt = b4[lane + 64 * k];
      t0 += dot4(w0[lane + 64 * k], bt);
      t1 += dot4(w1[lane + 64 * k], bt);
    }
    qs0 = rsum_u(s0);
    qs1 = rsum_u(s1);
    qb0 = rsum_u(t0);
    qb1 = rsum_u(t1);
  }

  float4 acc0[4], acc1[4];
#pragma unroll
  for (int k = 0; k < 4; ++k) {
    acc0[k] = make_float4(0.f, 0.f, 0.f, 0.f);
    acc1[k] = make_float4(0.f, 0.f, 0.f, 0.f);
  }
  float e0 = 0.f, e1 = 0.f, un0 = 0.f, un1 = 0.f;

  // per-row worker: stats (redundant per wave), 2 logits, softmax, accumulate
  auto process = [&](const float4& x0, const float4& x1,
                     const float4& x2, const float4& x3) {
    float ls = (x0.x + x0.y + x0.z + x0.w) + (x1.x + x1.y + x1.z + x1.w) +
               (x2.x + x2.y + x2.z + x2.w) + (x3.x + x3.y + x3.z + x3.w);
    float ls2 = dot4(x0, x0) + dot4(x1, x1) + dot4(x2, x2) + dot4(x3, x3);
    float d0 = dot4(qw0[0], x0) + dot4(qw0[1], x1) + dot4(qw0[2], x2) + dot4(qw0[3], x3);
    float d1 = dot4(qw1[0], x0) + dot4(qw1[1], x1) + dot4(qw1[2], x2) + dot4(qw1[3], x3);
    float LS = rsum_u(ls);
    float LS2 = rsum_u(ls2);
    float D0 = rsum_u(d0);
    float D1 = rsum_u(d1);
    float mu = LS * (1.f / CC);
    float rs = rsqrtf(LS2 * (1.f / CC) - mu * mu + EPS_);
    float l0 = fminf(rs * (D0 - mu * qs0) + qb0, 75.f);  // logits tiny; clamp = inf guard
    float l1 = fminf(rs * (D1 - mu * qs1) + qb1, 75.f);
    float p0 = __expf(l0), p1 = __expf(l1);
    float w0 = p0 * rs, w1 = p1 * rs;
    e0 += p0; e1 += p1;
    un0 += w0 * mu; un1 += w1 * mu;
    fma4(acc0[0], w0, x0); fma4(acc0[1], w0, x1);
    fma4(acc0[2], w0, x2); fma4(acc0[3], w0, x3);
    fma4(acc1[0], w1, x0); fma4(acc1[1], w1, x1);
    fma4(acc1[2], w1, x2); fma4(acc1[3], w1, x3);
  };

  // prologue: row 0 -> xA
  float4 xA0 = gx[lane], xA1 = gx[lane + 64], xA2 = gx[lane + 128], xA3 = gx[lane + 192];
  float4 xB0, xB1, xB2, xB3;

  for (int rq = 0; rq < RPB / 4; ++rq) {   // 16 quads of 4 rows
#pragma unroll
    for (int rp = 0; rp < 2; ++rp) {       // 2 row-pairs per quad
      const int r = rq * 4 + rp * 2;
      {  // issue row r+1 -> xB (in flight while processing xA)
        const float4* g1 = gx + (size_t)(r + 1) * 256;
        xB0 = g1[lane]; xB1 = g1[lane + 64]; xB2 = g1[lane + 128]; xB3 = g1[lane + 192];
      }
      process(xA0, xA1, xA2, xA3);         // row r
      {  // issue row r+2 -> xA (clamped refetch at the tail; harmless)
        const int r2 = (r + 2 < RPB) ? r + 2 : RPB - 1;
        const float4* g2 = gx + (size_t)r2 * 256;
        xA0 = g2[lane]; xA1 = g2[lane + 64]; xA2 = g2[lane + 128]; xA3 = g2[lane + 192];
      }
      process(xB0, xB1, xB2, xB3);         // row r+1
    }
    // bare alignment barrier: bounds wave drift so the block's 4 waves keep
    // reading the same lines (L1/L2 hit). Drains nothing.
    __builtin_amdgcn_s_barrier();
  }

  // ---- store partials
  float4* p0 = (float4*)(part_s + ((size_t)bc * HH + h0) * CC);
  float4* p1 = (float4*)(part_s + ((size_t)bc * HH + h0 + 1) * CC);
#pragma unroll
  for (int k = 0; k < 4; ++k) {
    p0[64 * k + lane] = acc0[k];
    p1[64 * k + lane] = acc1[k];
  }
  if (lane == 0) {
    float* pm = part_meu + ((size_t)bc * HH + h0) * 2;
    pm[0] = e0; pm[1] = un0;
    pm[2] = e1; pm[3] = un1;
  }
}

// ---- merge partials: s[b,h,c] = gamma*(S-UN)/E + beta ----
__global__ __launch_bounds__(256) void kmerge(
    const float* __restrict__ part_s, const float* __restrict__ part_meu,
    const float* __restrict__ kvg, const float* __restrict__ kvb,
    float* __restrict__ s) {
  int h = blockIdx.x >> 2, q = blockIdx.x & 3, b = blockIdx.y;
  int col = q * 256 + threadIdx.x;
  float E = 0.f, UN = 0.f, a = 0.f;
  for (int ch = 0; ch < CHUNKS; ++ch) {
    const float* pm = part_meu + (((size_t)b * CHUNKS + ch) * HH + h) * 2;
    E += pm[0];
    UN += pm[1];
    a += part_s[(((size_t)b * CHUNKS + ch) * HH + h) * CC + col];
  }
  float inv = 1.f / E;
  s[((size_t)b * HH + h) * CC + col] = kvg[col] * (a - UN) * inv + kvb[col];
}

// ---- k5: agg[b,j] = Wkv[C+j,:] . s[b, j/D, :] ----
__global__ __launch_bounds__(256) void k5(const float* __restrict__ Wkv,
                                          const float* __restrict__ s,
                                          float* __restrict__ agg) {
  int lane = threadIdx.x & 63;
  int j = blockIdx.x * 4 + (threadIdx.x >> 6);
  int h = j >> 7;
  const float4* wr = (const float4*)(Wkv + ((size_t)(CC + j)) * CC);
  float4 wv[4];
#pragma unroll
  for (int k = 0; k < 4; ++k) wv[k] = wr[lane + 64 * k];
  for (int b = 0; b < BB; ++b) {
    const float4* s4 = (const float4*)(s + ((size_t)(b * HH + h)) * CC);
    float a = 0.f;
#pragma unroll
    for (int k = 0; k < 4; ++k) a += dot4(wv[k], s4[lane + 64 * k]);
    a = wsum(a);
    if (lane == 0) agg[b * CC + j] = a;
  }
}

// ---- k6: out[b,j] = cf[j] + agg[b,:] . proj_W[j,:] + proj_b[j] ----
__global__ __launch_bounds__(256) void k6(const float* __restrict__ pW,
                                          const float* __restrict__ agg,
                                          const float* __restrict__ cf,
                                          const float* __restrict__ pb,
                                          float* __restrict__ out) {
  int lane = threadIdx.x & 63;
  int j = blockIdx.x * 4 + (threadIdx.x >> 6);
  const float4* wr = (const float4*)(pW + (size_t)j * CC);
  float4 wv[4];
#pragma unroll
  for (int k = 0; k < 4; ++k) wv[k] = wr[lane + 64 * k];
  for (int b = 0; b < BB; ++b) {
    const float4* a4 = (const float4*)(agg + (size_t)b * CC);
    float a = 0.f;
#pragma unroll
    for (int k = 0; k < 4; ++k) a += dot4(wv[k], a4[lane + 64 * k]);
    a = wsum(a);
    if (lane == 0) out[b * CC + j] = cf[j] + a + pb[j];
  }
}

// ws float offsets
constexpr size_t WS_QVEC = 0;        // 1024
constexpr size_t WS_QW   = 1024;     // 8192
constexpr size_t WS_QWG  = 9216;     // 8192
constexpr size_t WS_S    = 17408;    // 131072
constexpr size_t WS_AGG  = 148480;   // 16384
constexpr size_t WS_PMEU = 164864;   // 16384
constexpr size_t WS_PART = 181248;   // 8388608 (33.5 MB)

extern "C" void kernel_launch(void* const* d_in, const int* in_sizes, int n_in,
                              void* d_out, int out_size, void* d_ws, size_t ws_size,
                              hipStream_t stream) {
  const float* cf = (const float*)d_in[0];
  const float* x = (const float*)d_in[1];
  const float* qg = (const float*)d_in[2];
  const float* qb = (const float*)d_in[3];
  const float* Wq = (const float*)d_in[4];
  const float* kvg = (const float*)d_in[5];
  const float* kvb = (const float*)d_in[6];
  const float* Wkv = (const float*)d_in[7];
  const float* pW = (const float*)d_in[8];
  const float* pb = (const float*)d_in[9];
  float* ws = (float*)d_ws;
  float* out = (float*)d_out;

  k0b<<<256, 256, 0, stream>>>(cf, qg, qb, Wq, ws + WS_QVEC);
  k0c<<<128, 256, 0, stream>>>(ws + WS_QVEC, Wkv, kvg, ws + WS_QW, ws + WS_QWG);
  kfused<<<dim3(CHUNKS, BB), 256, 0, stream>>>(x, ws + WS_QWG, ws + WS_QW, kvb,
                                               ws + WS_PART, ws + WS_PMEU);
  kmerge<<<dim3(HH * 4, BB), 256, 0, stream>>>(ws + WS_PART, ws + WS_PMEU, kvg, kvb,
                                               ws + WS_S);
  k5<<<256, 256, 0, stream>>>(Wkv, ws + WS_S, ws + WS_AGG);
  k6<<<256, 256, 0, stream>>>(pW, ws + WS_AGG, cf, pb, out);
}

// Round 9
// 150.648 us; speedup vs baseline: 1.0177x; 1.0177x over previous
//
#include <hip/hip_runtime.h>
#include <math.h>

// GlobalAttention, single-streaming-pass version (v9).
//   logits[b,h,n] = qW[h,:].LN(x[b,n,:])  (q folded through Wkv_k, LN folded via mu/rstd)
//   s[b,h,:]      = sum_n softmax(logits) * rstd_n * x[b,n,:]  (chunk partials, merged)
//   out           = cf + (Wkv_v @ (gamma*(S-UN)/E + beta)) @ proj_W.T + proj_b
// v9: triple-buffered LDS, global_load_lds staging 2 tiles deep, counted
// s_waitcnt vmcnt(4) (never 0 in the main loop) + ONE s_barrier per tile.
// Stats computed redundantly per wave inside phase B (no stats phase, no
// reg-staging -> VGPR ~100). Epilogue tile drains vmcnt(0).

#define BB 16
#define NN 4096
#define CC 1024
#define HH 8
#define DD 128
#define CHUNKS 64   // chunks per batch
#define RPB 64      // rows per block
#define TPT 4       // rows per tile
#define NT 16       // tiles per block

constexpr float EPS_ = 1e-5f;
constexpr float SCALE_ = 0.03125f; // 1024^-0.5

__device__ __forceinline__ float wsum(float v) {
#pragma unroll
  for (int o = 32; o; o >>= 1) v += __shfl_xor(v, o, 64);
  return v;
}

// DPP wave reduction: sum of all 64 lanes lands in lane 63 (VALU pipe, no LDS).
__device__ __forceinline__ float dpp_sum63(float v) {
  int t;
  t = __builtin_amdgcn_update_dpp(0, __float_as_int(v), 0x111, 0xf, 0xf, true);  v += __int_as_float(t);
  t = __builtin_amdgcn_update_dpp(0, __float_as_int(v), 0x112, 0xf, 0xf, true);  v += __int_as_float(t);
  t = __builtin_amdgcn_update_dpp(0, __float_as_int(v), 0x114, 0xf, 0xf, true);  v += __int_as_float(t);
  t = __builtin_amdgcn_update_dpp(0, __float_as_int(v), 0x118, 0xf, 0xf, true);  v += __int_as_float(t);
  t = __builtin_amdgcn_update_dpp(0, __float_as_int(v), 0x142, 0xa, 0xf, false); v += __int_as_float(t);
  t = __builtin_amdgcn_update_dpp(0, __float_as_int(v), 0x143, 0xc, 0xf, false); v += __int_as_float(t);
  return v;
}

// reduce + broadcast: total of 64 lanes as a wave-uniform value
__device__ __forceinline__ float rsum_u(float v) {
  return __int_as_float(__builtin_amdgcn_readlane(__float_as_int(dpp_sum63(v)), 63));
}

__device__ __forceinline__ float dot4(const float4& a, const float4& b) {
  return a.x * b.x + a.y * b.y + a.z * b.z + a.w * b.w;
}
__device__ __forceinline__ void fma4(float4& a, float s, const float4& v) {
  a.x += s * v.x; a.y += s * v.y; a.z += s * v.z; a.w += s * v.w;
}

// counted-vmcnt barrier: tile ready, deeper prefetch stays in flight
__device__ __forceinline__ void bar_vm4() {
  asm volatile("s_waitcnt vmcnt(4)" ::: "memory");
  __builtin_amdgcn_sched_barrier(0);
  __builtin_amdgcn_s_barrier();
  __builtin_amdgcn_sched_barrier(0);
}
__device__ __forceinline__ void bar_vm0() {
  asm volatile("s_waitcnt vmcnt(0)" ::: "memory");
  __builtin_amdgcn_sched_barrier(0);
  __builtin_amdgcn_s_barrier();
  __builtin_amdgcn_sched_barrier(0);
}

// stage one 4-row tile (16 KB) into LDS: 4 x global_load_lds dwordx4 per thread.
__device__ __forceinline__ void stage_tile(const float* gsrc, float* lbase,
                                           int wid, int lane) {
#pragma unroll
  for (int k = 0; k < 4; ++k) {
    const char* g = (const char*)gsrc + k * 4096 + wid * 1024 + lane * 16;
    char* l = (char*)lbase + k * 4096 + wid * 1024;
    __builtin_amdgcn_global_load_lds(
        (const __attribute__((address_space(1))) void*)g,
        (__attribute__((address_space(3))) void*)l, 16, 0, 0);
  }
}

// ---- k0b: LN(class_feature) in-block, then qvec[j] = ln_cf . Wq[j,:] ----
__global__ __launch_bounds__(256) void k0b(const float* __restrict__ cf,
                                           const float* __restrict__ g,
                                           const float* __restrict__ be,
                                           const float* __restrict__ Wq,
                                           float* __restrict__ qvec) {
  __shared__ __align__(16) float lnbuf[CC];
  __shared__ float red[8];
  int t = threadIdx.x, lane = t & 63, wid = t >> 6;
  float x[4];
  float s = 0.f, s2 = 0.f;
#pragma unroll
  for (int j = 0; j < 4; ++j) {
    x[j] = cf[t * 4 + j];
    s += x[j];
    s2 += x[j] * x[j];
  }
  s = wsum(s);
  s2 = wsum(s2);
  if (lane == 0) { red[wid] = s; red[4 + wid] = s2; }
  __syncthreads();
  float S = red[0] + red[1] + red[2] + red[3];
  float S2 = red[4] + red[5] + red[6] + red[7];
  float mu = S * (1.f / CC);
  float rstd = rsqrtf(S2 * (1.f / CC) - mu * mu + EPS_);
#pragma unroll
  for (int j = 0; j < 4; ++j)
    lnbuf[t * 4 + j] = (x[j] - mu) * rstd * g[t * 4 + j] + be[t * 4 + j];
  __syncthreads();
  int j = blockIdx.x * 4 + wid;
  const float4* wr = (const float4*)(Wq + (size_t)j * CC);
  const float4* l4 = (const float4*)lnbuf;
  float a = 0.f;
#pragma unroll
  for (int k = 0; k < 4; ++k) a += dot4(wr[lane + 64 * k], l4[lane + 64 * k]);
  a = wsum(a);
  if (lane == 0) qvec[j] = a;
}

// ---- k0c: qW[h,c] = scale*sum_d qvec[h*D+d]*Wkv[h*D+d,c]; qWg = qW*gamma ----
__global__ __launch_bounds__(256) void k0c(const float* __restrict__ qvec,
                                           const float* __restrict__ Wkv,
                                           const float* __restrict__ kvg,
                                           float* __restrict__ qW,
                                           float* __restrict__ qWg) {
  int h = blockIdx.x >> 4;
  int c0 = (blockIdx.x & 15) * 64;
  int t = threadIdx.x, cl = t & 63, g = t >> 6;
  float a = 0.f;
#pragma unroll 8
  for (int d = g * 32; d < g * 32 + 32; ++d)
    a += qvec[h * DD + d] * Wkv[((size_t)(h * DD + d)) * CC + c0 + cl];
  __shared__ float red[4][64];
  red[g][cl] = a;
  __syncthreads();
  if (t < 64) {
    float v = (red[0][t] + red[1][t] + red[2][t] + red[3][t]) * SCALE_;
    qW[h * CC + c0 + t] = v;
    qWg[h * CC + c0 + t] = v * kvg[c0 + t];
  }
}

// ---- fused single pass over x (v9) ----
__global__ __launch_bounds__(256, 2) void kfused(
    const float* __restrict__ x, const float* __restrict__ qWg,
    const float* __restrict__ qW, const float* __restrict__ kvb,
    float* __restrict__ part_s, float* __restrict__ part_meu) {
  __shared__ __align__(16) float xbuf[3][TPT * CC];  // 3 x 16 KB

  const int t = threadIdx.x, lane = t & 63, wid = t >> 6;
  const int chunk = blockIdx.x, b = blockIdx.y;
  const int bc = b * CHUNKS + chunk;
  const int h0 = wid * 2;

  const float* gx = x + ((size_t)b * NN + (size_t)chunk * RPB) * CC;
  // prologue: stage tiles 0 and 1 (2-deep pipeline)
  stage_tile(gx, xbuf[0], wid, lane);
  stage_tile(gx + TPT * CC, xbuf[1], wid, lane);

  // this wave's two heads' qWg fragments (live across the whole loop)
  float4 qw0[4], qw1[4];
  {
    const float4* a0 = (const float4*)(qWg + (size_t)h0 * CC);
    const float4* a1 = (const float4*)(qWg + (size_t)(h0 + 1) * CC);
#pragma unroll
    for (int k = 0; k < 4; ++k) {
      qw0[k] = a0[lane + 64 * k];
      qw1[k] = a1[lane + 64 * k];
    }
  }
  // qs = sum(qWg[h,:]); qb = qW[h,:].beta  (wave-uniform)
  float qs0, qs1, qb0, qb1;
  {
    float s0 = 0.f, s1 = 0.f, t0 = 0.f, t1 = 0.f;
    const float4* w0 = (const float4*)(qW + (size_t)h0 * CC);
    const float4* w1 = (const float4*)(qW + (size_t)(h0 + 1) * CC);
    const float4* b4 = (const float4*)kvb;
#pragma unroll
    for (int k = 0; k < 4; ++k) {
      s0 += qw0[k].x + qw0[k].y + qw0[k].z + qw0[k].w;
      s1 += qw1[k].x + qw1[k].y + qw1[k].z + qw1[k].w;
      float4 bt = b4[lane + 64 * k];
      t0 += dot4(w0[lane + 64 * k], bt);
      t1 += dot4(w1[lane + 64 * k], bt);
    }
    qs0 = rsum_u(s0);
    qs1 = rsum_u(s1);
    qb0 = rsum_u(t0);
    qb1 = rsum_u(t1);
  }

  float4 acc0[4], acc1[4];
#pragma unroll
  for (int k = 0; k < 4; ++k) {
    acc0[k] = make_float4(0.f, 0.f, 0.f, 0.f);
    acc1[k] = make_float4(0.f, 0.f, 0.f, 0.f);
  }
  float e0 = 0.f, e1 = 0.f, un0 = 0.f, un1 = 0.f;

  // phase B worker for one tile (redundant per-wave stats; branchless)
  auto phaseB = [&](const float* buf) {
    const float4* xb4 = (const float4*)buf;
#pragma unroll
    for (int r = 0; r < TPT; ++r) {
      float4 x0 = xb4[r * 256 + lane];
      float4 x1 = xb4[r * 256 + lane + 64];
      float4 x2 = xb4[r * 256 + lane + 128];
      float4 x3 = xb4[r * 256 + lane + 192];
      float ls = (x0.x + x0.y + x0.z + x0.w) + (x1.x + x1.y + x1.z + x1.w) +
                 (x2.x + x2.y + x2.z + x2.w) + (x3.x + x3.y + x3.z + x3.w);
      float ls2 = dot4(x0, x0) + dot4(x1, x1) + dot4(x2, x2) + dot4(x3, x3);
      float d0 = dot4(qw0[0], x0) + dot4(qw0[1], x1) + dot4(qw0[2], x2) + dot4(qw0[3], x3);
      float d1 = dot4(qw1[0], x0) + dot4(qw1[1], x1) + dot4(qw1[2], x2) + dot4(qw1[3], x3);
      // 4 independent DPP chains -> interleave hides latency
      float LS = rsum_u(ls);
      float LS2 = rsum_u(ls2);
      float D0 = rsum_u(d0);
      float D1 = rsum_u(d1);
      float mu = LS * (1.f / CC);
      float rs = rsqrtf(LS2 * (1.f / CC) - mu * mu + EPS_);
      float l0 = fminf(rs * (D0 - mu * qs0) + qb0, 75.f);  // logits tiny; clamp = inf guard
      float l1 = fminf(rs * (D1 - mu * qs1) + qb1, 75.f);
      float p0 = __expf(l0), p1 = __expf(l1);
      float w0 = p0 * rs, w1 = p1 * rs;
      e0 += p0; e1 += p1;
      un0 += w0 * mu; un1 += w1 * mu;
      fma4(acc0[0], w0, x0); fma4(acc0[1], w0, x1);
      fma4(acc0[2], w0, x2); fma4(acc0[3], w0, x3);
      fma4(acc1[0], w1, x0); fma4(acc1[1], w1, x1);
      fma4(acc1[2], w1, x2); fma4(acc1[3], w1, x3);
    }
  };

  int cur = 0;
  for (int tl = 0; tl < NT - 1; ++tl) {
    // tile tl ready (its 4 loads are older than the newest 4); tl+1 may be in flight
    bar_vm4();
    if (tl + 2 < NT) {
      int slot = cur + 2;
      if (slot >= 3) slot -= 3;
      stage_tile(gx + (size_t)(tl + 2) * (TPT * CC), xbuf[slot], wid, lane);
    }
    phaseB(xbuf[cur]);
    cur = (cur + 1 == 3) ? 0 : cur + 1;
  }
  bar_vm0();  // last tile: drain
  phaseB(xbuf[cur]);

  // ---- store partials
  float4* p0 = (float4*)(part_s + ((size_t)bc * HH + h0) * CC);
  float4* p1 = (float4*)(part_s + ((size_t)bc * HH + h0 + 1) * CC);
#pragma unroll
  for (int k = 0; k < 4; ++k) {
    p0[64 * k + lane] = acc0[k];
    p1[64 * k + lane] = acc1[k];
  }
  if (lane == 0) {
    float* pm = part_meu + ((size_t)bc * HH + h0) * 2;
    pm[0] = e0; pm[1] = un0;
    pm[2] = e1; pm[3] = un1;
  }
}

// ---- merge partials: s[b,h,c] = gamma*(S-UN)/E + beta ----
__global__ __launch_bounds__(256) void kmerge(
    const float* __restrict__ part_s, const float* __restrict__ part_meu,
    const float* __restrict__ kvg, const float* __restrict__ kvb,
    float* __restrict__ s) {
  int h = blockIdx.x >> 2, q = blockIdx.x & 3, b = blockIdx.y;
  int col = q * 256 + threadIdx.x;
  float E = 0.f, UN = 0.f, a = 0.f;
  for (int ch = 0; ch < CHUNKS; ++ch) {
    const float* pm = part_meu + (((size_t)b * CHUNKS + ch) * HH + h) * 2;
    E += pm[0];
    UN += pm[1];
    a += part_s[(((size_t)b * CHUNKS + ch) * HH + h) * CC + col];
  }
  float inv = 1.f / E;
  s[((size_t)b * HH + h) * CC + col] = kvg[col] * (a - UN) * inv + kvb[col];
}

// ---- k5: agg[b,j] = Wkv[C+j,:] . s[b, j/D, :] ----
__global__ __launch_bounds__(256) void k5(const float* __restrict__ Wkv,
                                          const float* __restrict__ s,
                                          float* __restrict__ agg) {
  int lane = threadIdx.x & 63;
  int j = blockIdx.x * 4 + (threadIdx.x >> 6);
  int h = j >> 7;
  const float4* wr = (const float4*)(Wkv + ((size_t)(CC + j)) * CC);
  float4 wv[4];
#pragma unroll
  for (int k = 0; k < 4; ++k) wv[k] = wr[lane + 64 * k];
  for (int b = 0; b < BB; ++b) {
    const float4* s4 = (const float4*)(s + ((size_t)(b * HH + h)) * CC);
    float a = 0.f;
#pragma unroll
    for (int k = 0; k < 4; ++k) a += dot4(wv[k], s4[lane + 64 * k]);
    a = wsum(a);
    if (lane == 0) agg[b * CC + j] = a;
  }
}

// ---- k6: out[b,j] = cf[j] + agg[b,:] . proj_W[j,:] + proj_b[j] ----
__global__ __launch_bounds__(256) void k6(const float* __restrict__ pW,
                                          const float* __restrict__ agg,
                                          const float* __restrict__ cf,
                                          const float* __restrict__ pb,
                                          float* __restrict__ out) {
  int lane = threadIdx.x & 63;
  int j = blockIdx.x * 4 + (threadIdx.x >> 6);
  const float4* wr = (const float4*)(pW + (size_t)j * CC);
  float4 wv[4];
#pragma unroll
  for (int k = 0; k < 4; ++k) wv[k] = wr[lane + 64 * k];
  for (int b = 0; b < BB; ++b) {
    const float4* a4 = (const float4*)(agg + (size_t)b * CC);
    float a = 0.f;
#pragma unroll
    for (int k = 0; k < 4; ++k) a += dot4(wv[k], a4[lane + 64 * k]);
    a = wsum(a);
    if (lane == 0) out[b * CC + j] = cf[j] + a + pb[j];
  }
}

// ws float offsets
constexpr size_t WS_QVEC = 0;        // 1024
constexpr size_t WS_QW   = 1024;     // 8192
constexpr size_t WS_QWG  = 9216;     // 8192
constexpr size_t WS_S    = 17408;    // 131072
constexpr size_t WS_AGG  = 148480;   // 16384
constexpr size_t WS_PMEU = 164864;   // 16384
constexpr size_t WS_PART = 181248;   // 8388608 (33.5 MB)

extern "C" void kernel_launch(void* const* d_in, const int* in_sizes, int n_in,
                              void* d_out, int out_size, void* d_ws, size_t ws_size,
                              hipStream_t stream) {
  const float* cf = (const float*)d_in[0];
  const float* x = (const float*)d_in[1];
  const float* qg = (const float*)d_in[2];
  const float* qb = (const float*)d_in[3];
  const float* Wq = (const float*)d_in[4];
  const float* kvg = (const float*)d_in[5];
  const float* kvb = (const float*)d_in[6];
  const float* Wkv = (const float*)d_in[7];
  const float* pW = (const float*)d_in[8];
  const float* pb = (const float*)d_in[9];
  float* ws = (float*)d_ws;
  float* out = (float*)d_out;

  k0b<<<256, 256, 0, stream>>>(cf, qg, qb, Wq, ws + WS_QVEC);
  k0c<<<128, 256, 0, stream>>>(ws + WS_QVEC, Wkv, kvg, ws + WS_QW, ws + WS_QWG);
  kfused<<<dim3(CHUNKS, BB), 256, 0, stream>>>(x, ws + WS_QWG, ws + WS_QW, kvb,
                                               ws + WS_PART, ws + WS_PMEU);
  kmerge<<<dim3(HH * 4, BB), 256, 0, stream>>>(ws + WS_PART, ws + WS_PMEU, kvg, kvb,
                                               ws + WS_S);
  k5<<<256, 256, 0, stream>>>(Wkv, ws + WS_S, ws + WS_AGG);
  k6<<<256, 256, 0, stream>>>(pW, ws + WS_AGG, cf, pb, out);
}

// Round 10
// 117.196 us; speedup vs baseline: 1.3082x; 1.2854x over previous
//
#include <hip/hip_runtime.h>
#include <math.h>

// GlobalAttention, single-streaming-pass version (v10).
//   logits[b,h,n] = qW[h,:].LN(x[b,n,:])  (q folded through Wkv_k, LN folded via mu/rstd)
//   s[b,h,:]      = sum_n softmax(logits) * rstd_n * x[b,n,:]  (chunk partials, merged)
//   out           = cf + (Wkv_v @ (gamma*(S-UN)/E + beta)) @ proj_W.T + proj_b
// v10: global_load_lds staging where EACH WAVE STAGES ITS OWN ROW of the 4-row
// tile. Schedule per tile: [vmcnt(0) on own loads -> stats from own row (no
// barrier) -> ONE bar_lgkm -> issue tile tl+1 -> phase B]. Non-redundant stats,
// 1 barrier/tile, no pf registers -> VGPR ~96 -> 4 blocks/CU guaranteed.

#define BB 16
#define NN 4096
#define CC 1024
#define HH 8
#define DD 128
#define CHUNKS 64   // chunks per batch
#define RPB 64      // rows per block
#define TPT 4       // rows per tile
#define NT 16       // tiles per block

constexpr float EPS_ = 1e-5f;
constexpr float SCALE_ = 0.03125f; // 1024^-0.5

__device__ __forceinline__ float wsum(float v) {
#pragma unroll
  for (int o = 32; o; o >>= 1) v += __shfl_xor(v, o, 64);
  return v;
}

// DPP wave reduction: sum of all 64 lanes lands in lane 63 (VALU pipe, no LDS).
__device__ __forceinline__ float dpp_sum63(float v) {
  int t;
  t = __builtin_amdgcn_update_dpp(0, __float_as_int(v), 0x111, 0xf, 0xf, true);  v += __int_as_float(t);
  t = __builtin_amdgcn_update_dpp(0, __float_as_int(v), 0x112, 0xf, 0xf, true);  v += __int_as_float(t);
  t = __builtin_amdgcn_update_dpp(0, __float_as_int(v), 0x114, 0xf, 0xf, true);  v += __int_as_float(t);
  t = __builtin_amdgcn_update_dpp(0, __float_as_int(v), 0x118, 0xf, 0xf, true);  v += __int_as_float(t);
  t = __builtin_amdgcn_update_dpp(0, __float_as_int(v), 0x142, 0xa, 0xf, false); v += __int_as_float(t);
  t = __builtin_amdgcn_update_dpp(0, __float_as_int(v), 0x143, 0xc, 0xf, false); v += __int_as_float(t);
  return v;
}

// reduce + broadcast: total of 64 lanes as a wave-uniform value
__device__ __forceinline__ float rsum_u(float v) {
  return __int_as_float(__builtin_amdgcn_readlane(__float_as_int(dpp_sum63(v)), 63));
}

__device__ __forceinline__ float dot4(const float4& a, const float4& b) {
  return a.x * b.x + a.y * b.y + a.z * b.z + a.w * b.w;
}
__device__ __forceinline__ void fma4(float4& a, float s, const float4& v) {
  a.x += s * v.x; a.y += s * v.y; a.z += s * v.z; a.w += s * v.w;
}

// barrier that waits LDS ops only (keeps global_load_lds prefetch in flight)
__device__ __forceinline__ void bar_lgkm() {
  asm volatile("s_waitcnt lgkmcnt(0)" ::: "memory");
  __builtin_amdgcn_sched_barrier(0);
  __builtin_amdgcn_s_barrier();
  __builtin_amdgcn_sched_barrier(0);
}

// wait for MY outstanding global_load_lds (own row staged); no barrier
__device__ __forceinline__ void wait_vm0() {
  asm volatile("s_waitcnt vmcnt(0)" ::: "memory");
  __builtin_amdgcn_sched_barrier(0);
}

// stage one 4-row tile (16 KB): WAVE wid stages ROW wid entirely
// (4 x global_load_lds dwordx4: 1 KB contiguous per instruction).
__device__ __forceinline__ void stage_tile(const float* gsrc, float* lbase,
                                           int wid, int lane) {
#pragma unroll
  for (int k = 0; k < 4; ++k) {
    const char* g = (const char*)gsrc + wid * 4096 + k * 1024 + lane * 16;
    char* l = (char*)lbase + wid * 4096 + k * 1024;
    __builtin_amdgcn_global_load_lds(
        (const __attribute__((address_space(1))) void*)g,
        (__attribute__((address_space(3))) void*)l, 16, 0, 0);
  }
}

// ---- k0b: LN(class_feature) in-block, then qvec[j] = ln_cf . Wq[j,:] ----
__global__ __launch_bounds__(256) void k0b(const float* __restrict__ cf,
                                           const float* __restrict__ g,
                                           const float* __restrict__ be,
                                           const float* __restrict__ Wq,
                                           float* __restrict__ qvec) {
  __shared__ __align__(16) float lnbuf[CC];
  __shared__ float red[8];
  int t = threadIdx.x, lane = t & 63, wid = t >> 6;
  float x[4];
  float s = 0.f, s2 = 0.f;
#pragma unroll
  for (int j = 0; j < 4; ++j) {
    x[j] = cf[t * 4 + j];
    s += x[j];
    s2 += x[j] * x[j];
  }
  s = wsum(s);
  s2 = wsum(s2);
  if (lane == 0) { red[wid] = s; red[4 + wid] = s2; }
  __syncthreads();
  float S = red[0] + red[1] + red[2] + red[3];
  float S2 = red[4] + red[5] + red[6] + red[7];
  float mu = S * (1.f / CC);
  float rstd = rsqrtf(S2 * (1.f / CC) - mu * mu + EPS_);
#pragma unroll
  for (int j = 0; j < 4; ++j)
    lnbuf[t * 4 + j] = (x[j] - mu) * rstd * g[t * 4 + j] + be[t * 4 + j];
  __syncthreads();
  int j = blockIdx.x * 4 + wid;
  const float4* wr = (const float4*)(Wq + (size_t)j * CC);
  const float4* l4 = (const float4*)lnbuf;
  float a = 0.f;
#pragma unroll
  for (int k = 0; k < 4; ++k) a += dot4(wr[lane + 64 * k], l4[lane + 64 * k]);
  a = wsum(a);
  if (lane == 0) qvec[j] = a;
}

// ---- k0c: qW[h,c] = scale*sum_d qvec[h*D+d]*Wkv[h*D+d,c]; qWg = qW*gamma ----
__global__ __launch_bounds__(256) void k0c(const float* __restrict__ qvec,
                                           const float* __restrict__ Wkv,
                                           const float* __restrict__ kvg,
                                           float* __restrict__ qW,
                                           float* __restrict__ qWg) {
  int h = blockIdx.x >> 4;
  int c0 = (blockIdx.x & 15) * 64;
  int t = threadIdx.x, cl = t & 63, g = t >> 6;
  float a = 0.f;
#pragma unroll 8
  for (int d = g * 32; d < g * 32 + 32; ++d)
    a += qvec[h * DD + d] * Wkv[((size_t)(h * DD + d)) * CC + c0 + cl];
  __shared__ float red[4][64];
  red[g][cl] = a;
  __syncthreads();
  if (t < 64) {
    float v = (red[0][t] + red[1][t] + red[2][t] + red[3][t]) * SCALE_;
    qW[h * CC + c0 + t] = v;
    qWg[h * CC + c0 + t] = v * kvg[c0 + t];
  }
}

// ---- fused single pass over x (v10) ----
__global__ __launch_bounds__(256, 2) void kfused(
    const float* __restrict__ x, const float* __restrict__ qWg,
    const float* __restrict__ qW, const float* __restrict__ kvb,
    float* __restrict__ part_s, float* __restrict__ part_meu) {
  __shared__ __align__(16) float xbuf[2][TPT * CC];  // 2 x 16 KB
  __shared__ __align__(8) float mr_lds[2][TPT][2];   // {mu, rstd} double-buffered

  const int t = threadIdx.x, lane = t & 63, wid = t >> 6;
  const int chunk = blockIdx.x, b = blockIdx.y;
  const int bc = b * CHUNKS + chunk;
  const int h0 = wid * 2;

  const float* gx = x + ((size_t)b * NN + (size_t)chunk * RPB) * CC;
  stage_tile(gx, xbuf[0], wid, lane);  // tile 0 in flight during prologue math

  // this wave's two heads' qWg fragments (live across the whole loop)
  float4 qw0[4], qw1[4];
  {
    const float4* a0 = (const float4*)(qWg + (size_t)h0 * CC);
    const float4* a1 = (const float4*)(qWg + (size_t)(h0 + 1) * CC);
#pragma unroll
    for (int k = 0; k < 4; ++k) {
      qw0[k] = a0[lane + 64 * k];
      qw1[k] = a1[lane + 64 * k];
    }
  }
  // qs = sum(qWg[h,:]); qb = qW[h,:].beta  (wave-uniform)
  float qs0, qs1, qb0, qb1;
  {
    float s0 = 0.f, s1 = 0.f, t0 = 0.f, t1 = 0.f;
    const float4* w0 = (const float4*)(qW + (size_t)h0 * CC);
    const float4* w1 = (const float4*)(qW + (size_t)(h0 + 1) * CC);
    const float4* b4 = (const float4*)kvb;
#pragma unroll
    for (int k = 0; k < 4; ++k) {
      s0 += qw0[k].x + qw0[k].y + qw0[k].z + qw0[k].w;
      s1 += qw1[k].x + qw1[k].y + qw1[k].z + qw1[k].w;
      float4 bt = b4[lane + 64 * k];
      t0 += dot4(w0[lane + 64 * k], bt);
      t1 += dot4(w1[lane + 64 * k], bt);
    }
    qs0 = rsum_u(s0);
    qs1 = rsum_u(s1);
    qb0 = rsum_u(t0);
    qb1 = rsum_u(t1);
  }

  float4 acc0[4], acc1[4];
#pragma unroll
  for (int k = 0; k < 4; ++k) {
    acc0[k] = make_float4(0.f, 0.f, 0.f, 0.f);
    acc1[k] = make_float4(0.f, 0.f, 0.f, 0.f);
  }
  float e0 = 0.f, e1 = 0.f, un0 = 0.f, un1 = 0.f;

  for (int tl = 0; tl < NT; ++tl) {
    const int cur = tl & 1;

    // 1) my 4 staging loads for tile tl are done -> MY row (wid) is in LDS.
    wait_vm0();

    // 2) stats for row 'wid' from my own staged row (no barrier needed).
    {
      const float4* xr = (const float4*)xbuf[cur] + wid * 256;
      float4 x0 = xr[lane], x1 = xr[lane + 64], x2 = xr[lane + 128], x3 = xr[lane + 192];
      float ls = (x0.x + x0.y + x0.z + x0.w) + (x1.x + x1.y + x1.z + x1.w) +
                 (x2.x + x2.y + x2.z + x2.w) + (x3.x + x3.y + x3.z + x3.w);
      float ls2 = dot4(x0, x0) + dot4(x1, x1) + dot4(x2, x2) + dot4(x3, x3);
      ls = dpp_sum63(ls);
      ls2 = dpp_sum63(ls2);
      if (lane == 63) {
        float mu = ls * (1.f / CC);
        float rs = rsqrtf(ls2 * (1.f / CC) - mu * mu + EPS_);
        mr_lds[cur][wid][0] = mu;
        mr_lds[cur][wid][1] = rs;
      }
    }

    // 3) ONE barrier: mr + whole tile visible (everyone passed their vmcnt);
    //    everyone done reading buffer cur^1 -> safe to overwrite it.
    bar_lgkm();

    // 4) issue next tile's staging into the freed buffer (stays in flight
    //    across phase B; consumed at next iteration's wait_vm0).
    if (tl + 1 < NT)
      stage_tile(gx + (size_t)(tl + 1) * (TPT * CC), xbuf[cur ^ 1], wid, lane);

    // 5) phase B: branchless; this wave's 2 heads, all 4 rows
    const float4* xb4 = (const float4*)xbuf[cur];
#pragma unroll
    for (int r = 0; r < TPT; ++r) {
      float4 x0 = xb4[r * 256 + lane];
      float4 x1 = xb4[r * 256 + lane + 64];
      float4 x2 = xb4[r * 256 + lane + 128];
      float4 x3 = xb4[r * 256 + lane + 192];
      float a0 = dot4(qw0[0], x0), a1 = dot4(qw0[1], x1);
      float a2 = dot4(qw0[2], x2), a3 = dot4(qw0[3], x3);
      float c0 = dot4(qw1[0], x0), c1 = dot4(qw1[1], x1);
      float c2 = dot4(qw1[2], x2), c3 = dot4(qw1[3], x3);
      float D0 = rsum_u((a0 + a1) + (a2 + a3));
      float D1 = rsum_u((c0 + c1) + (c2 + c3));
      float2 mr = *(const float2*)mr_lds[cur][r];  // broadcast read
      float mu = mr.x, rs = mr.y;
      float l0 = fminf(rs * (D0 - mu * qs0) + qb0, 75.f);  // logits tiny; clamp = inf guard
      float l1 = fminf(rs * (D1 - mu * qs1) + qb1, 75.f);
      float p0 = __expf(l0), p1 = __expf(l1);
      float w0 = p0 * rs, w1 = p1 * rs;
      e0 += p0; e1 += p1;
      un0 += w0 * mu; un1 += w1 * mu;
      fma4(acc0[0], w0, x0); fma4(acc0[1], w0, x1);
      fma4(acc0[2], w0, x2); fma4(acc0[3], w0, x3);
      fma4(acc1[0], w1, x0); fma4(acc1[1], w1, x1);
      fma4(acc1[2], w1, x2); fma4(acc1[3], w1, x3);
    }
  }

  // ---- store partials (m == 0 by construction; logits bounded ~|2|)
  float4* p0 = (float4*)(part_s + ((size_t)bc * HH + h0) * CC);
  float4* p1 = (float4*)(part_s + ((size_t)bc * HH + h0 + 1) * CC);
#pragma unroll
  for (int k = 0; k < 4; ++k) {
    p0[64 * k + lane] = acc0[k];
    p1[64 * k + lane] = acc1[k];
  }
  if (lane == 0) {
    float* pm = part_meu + ((size_t)bc * HH + h0) * 2;
    pm[0] = e0; pm[1] = un0;
    pm[2] = e1; pm[3] = un1;
  }
}

// ---- merge partials: s[b,h,c] = gamma*(S-UN)/E + beta ----
__global__ __launch_bounds__(256) void kmerge(
    const float* __restrict__ part_s, const float* __restrict__ part_meu,
    const float* __restrict__ kvg, const float* __restrict__ kvb,
    float* __restrict__ s) {
  int h = blockIdx.x >> 2, q = blockIdx.x & 3, b = blockIdx.y;
  int col = q * 256 + threadIdx.x;
  float E = 0.f, UN = 0.f, a = 0.f;
  for (int ch = 0; ch < CHUNKS; ++ch) {
    const float* pm = part_meu + (((size_t)b * CHUNKS + ch) * HH + h) * 2;
    E += pm[0];
    UN += pm[1];
    a += part_s[(((size_t)b * CHUNKS + ch) * HH + h) * CC + col];
  }
  float inv = 1.f / E;
  s[((size_t)b * HH + h) * CC + col] = kvg[col] * (a - UN) * inv + kvb[col];
}

// ---- k5: agg[b,j] = Wkv[C+j,:] . s[b, j/D, :] ----
__global__ __launch_bounds__(256) void k5(const float* __restrict__ Wkv,
                                          const float* __restrict__ s,
                                          float* __restrict__ agg) {
  int lane = threadIdx.x & 63;
  int j = blockIdx.x * 4 + (threadIdx.x >> 6);
  int h = j >> 7;
  const float4* wr = (const float4*)(Wkv + ((size_t)(CC + j)) * CC);
  float4 wv[4];
#pragma unroll
  for (int k = 0; k < 4; ++k) wv[k] = wr[lane + 64 * k];
  for (int b = 0; b < BB; ++b) {
    const float4* s4 = (const float4*)(s + ((size_t)(b * HH + h)) * CC);
    float a = 0.f;
#pragma unroll
    for (int k = 0; k < 4; ++k) a += dot4(wv[k], s4[lane + 64 * k]);
    a = wsum(a);
    if (lane == 0) agg[b * CC + j] = a;
  }
}

// ---- k6: out[b,j] = cf[j] + agg[b,:] . proj_W[j,:] + proj_b[j] ----
__global__ __launch_bounds__(256) void k6(const float* __restrict__ pW,
                                          const float* __restrict__ agg,
                                          const float* __restrict__ cf,
                                          const float* __restrict__ pb,
                                          float* __restrict__ out) {
  int lane = threadIdx.x & 63;
  int j = blockIdx.x * 4 + (threadIdx.x >> 6);
  const float4* wr = (const float4*)(pW + (size_t)j * CC);
  float4 wv[4];
#pragma unroll
  for (int k = 0; k < 4; ++k) wv[k] = wr[lane + 64 * k];
  for (int b = 0; b < BB; ++b) {
    const float4* a4 = (const float4*)(agg + (size_t)b * CC);
    float a = 0.f;
#pragma unroll
    for (int k = 0; k < 4; ++k) a += dot4(wv[k], a4[lane + 64 * k]);
    a = wsum(a);
    if (lane == 0) out[b * CC + j] = cf[j] + a + pb[j];
  }
}

// ws float offsets
constexpr size_t WS_QVEC = 0;        // 1024
constexpr size_t WS_QW   = 1024;     // 8192
constexpr size_t WS_QWG  = 9216;     // 8192
constexpr size_t WS_S    = 17408;    // 131072
constexpr size_t WS_AGG  = 148480;   // 16384
constexpr size_t WS_PMEU = 164864;   // 16384
constexpr size_t WS_PART = 181248;   // 8388608 (33.5 MB)

extern "C" void kernel_launch(void* const* d_in, const int* in_sizes, int n_in,
                              void* d_out, int out_size, void* d_ws, size_t ws_size,
                              hipStream_t stream) {
  const float* cf = (const float*)d_in[0];
  const float* x = (const float*)d_in[1];
  const float* qg = (const float*)d_in[2];
  const float* qb = (const float*)d_in[3];
  const float* Wq = (const float*)d_in[4];
  const float* kvg = (const float*)d_in[5];
  const float* kvb = (const float*)d_in[6];
  const float* Wkv = (const float*)d_in[7];
  const float* pW = (const float*)d_in[8];
  const float* pb = (const float*)d_in[9];
  float* ws = (float*)d_ws;
  float* out = (float*)d_out;

  k0b<<<256, 256, 0, stream>>>(cf, qg, qb, Wq, ws + WS_QVEC);
  k0c<<<128, 256, 0, stream>>>(ws + WS_QVEC, Wkv, kvg, ws + WS_QW, ws + WS_QWG);
  kfused<<<dim3(CHUNKS, BB), 256, 0, stream>>>(x, ws + WS_QWG, ws + WS_QW, kvb,
                                               ws + WS_PART, ws + WS_PMEU);
  kmerge<<<dim3(HH * 4, BB), 256, 0, stream>>>(ws + WS_PART, ws + WS_PMEU, kvg, kvb,
                                               ws + WS_S);
  k5<<<256, 256, 0, stream>>>(Wkv, ws + WS_S, ws + WS_AGG);
  k6<<<256, 256, 0, stream>>>(pW, ws + WS_AGG, cf, pb, out);
}